// Round 1
// baseline (420.958 us; speedup 1.0000x reference)
//
#include <hip/hip_runtime.h>
#include <stdint.h>

typedef _Float16 half8 __attribute__((ext_vector_type(8)));
typedef float floatx4 __attribute__((ext_vector_type(4)));

#define TT 4096
#define DH 512

__device__ __forceinline__ unsigned short f2h(float f) {
    union { _Float16 h; unsigned short u; } v;
    v.h = (_Float16)f;
    return v.u;
}

// ---------- kernel 1: normalize right half of x -> xn (fp16), one wave per row ----------
__global__ void norm_k(const float* __restrict__ x, unsigned short* __restrict__ xn) {
    const int w = threadIdx.x >> 6, l = threadIdx.x & 63;
    const int row = blockIdx.x * 4 + w;              // 0 .. B*T-1
    const float* src = x + (size_t)row * 1024 + 512 + l * 8;
    floatx4 a = *(const floatx4*)src;
    floatx4 c = *(const floatx4*)(src + 4);
    float s = a[0]*a[0] + a[1]*a[1] + a[2]*a[2] + a[3]*a[3]
            + c[0]*c[0] + c[1]*c[1] + c[2]*c[2] + c[3]*c[3];
    #pragma unroll
    for (int off = 32; off > 0; off >>= 1) s += __shfl_xor(s, off);
    const float scale = 1.0f / fmaxf(sqrtf(s), 1e-12f);
    float v[8] = {a[0], a[1], a[2], a[3], c[0], c[1], c[2], c[3]};
    uint32_t pk[4];
    #pragma unroll
    for (int i = 0; i < 4; i++)
        pk[i] = (uint32_t)f2h(v[2*i] * scale) | ((uint32_t)f2h(v[2*i+1] * scale) << 16);
    uint4 o; o.x = pk[0]; o.y = pk[1]; o.z = pk[2]; o.w = pk[3];
    *(uint4*)(xn + (size_t)row * DH + l * 8) = o;
}

// ---------- kernel 2: xnT[b][d][t] = xn[b][t][d], 64x64 LDS tile transpose ----------
__global__ void transpose_k(const unsigned short* __restrict__ xn,
                            unsigned short* __restrict__ xnT) {
    __shared__ __align__(16) unsigned short tile[64 * 72];  // +8 pad
    const int b = blockIdx.z;
    const int t0 = blockIdx.x * 64, d0 = blockIdx.y * 64;
    const int tid = threadIdx.x;
    #pragma unroll
    for (int i = 0; i < 2; i++) {
        int c = i * 256 + tid;
        int tr = c >> 3, d8 = c & 7;
        uint4 vv = *(const uint4*)(xn + ((size_t)(b * TT + t0 + tr) * DH + d0 + d8 * 8));
        *(uint4*)&tile[tr * 72 + d8 * 8] = vv;
    }
    __syncthreads();
    #pragma unroll
    for (int i = 0; i < 2; i++) {
        int c = i * 256 + tid;
        int dd = c >> 3, t8 = c & 7;
        uint32_t pk[4];
        #pragma unroll
        for (int k = 0; k < 4; k++) {
            uint32_t h0 = tile[(t8 * 8 + 2 * k    ) * 72 + dd];
            uint32_t h1 = tile[(t8 * 8 + 2 * k + 1) * 72 + dd];
            pk[k] = h0 | (h1 << 16);
        }
        uint4 o; o.x = pk[0]; o.y = pk[1]; o.z = pk[2]; o.w = pk[3];
        *(uint4*)(xnT + ((size_t)(b * DH + d0 + dd) * TT + t0 + t8 * 8)) = o;
    }
}

// ---------- kernel 3: fused  ctx = (V .* (Q Kn^T)) Kn ;  out = x_left * sigmoid(ctx+bias) ----------
// grid (64 q-tiles, 4 batches), 256 threads = 4 waves, wave owns 16 q-rows.
__global__ __launch_bounds__(256, 1) void fused_k(
    const unsigned short* __restrict__ xn, const unsigned short* __restrict__ xnT,
    const float* __restrict__ V, const float* __restrict__ bias,
    const float* __restrict__ x, float* __restrict__ out)
{
    __shared__ __align__(16) unsigned short knL[64 * 512];   // Kn tile  [kk][d], swizzled
    __shared__ __align__(16) unsigned short ktL[512 * 64];   // Kn^T tile [d][kk], swizzled
    __shared__ __align__(16) unsigned short wtL[4 * 16 * 80]; // per-wave W scratch, swizzled

    const int tid = threadIdx.x;
    const int w = tid >> 6, l = tid & 63;
    const int lo = l & 15, g = l >> 4;
    const int qt = blockIdx.x, b = blockIdx.y;
    const int q0w = qt * 64 + w * 16;

    const unsigned short* xnb = xn  + (size_t)b * TT * DH;
    const unsigned short* xtb = xnT + (size_t)b * DH * TT;

    // Q fragments in registers: A[m=lo][k = s*32 + g*8 + j]
    half8 qf[16];
    #pragma unroll
    for (int s = 0; s < 16; s++)
        qf[s] = *(const half8*)(xnb + (size_t)(q0w + lo) * DH + s * 32 + g * 8);

    floatx4 acc[32];
    #pragma unroll
    for (int n = 0; n < 32; n++) acc[n] = (floatx4){0.f, 0.f, 0.f, 0.f};

    unsigned short* wt = wtL + w * (16 * 80);
    const int sx = lo & 7;  // row&7 swizzle term shared by all frag reads

    for (int kt = 0; kt < 64; kt++) {
        const int k0 = kt * 64;

        // ---- stage Kn [row=kk][d], 16B chunks, chunk-index XOR-swizzled by row&7 ----
        #pragma unroll
        for (int i = 0; i < 16; i++) {
            int p = i * 256 + tid;
            int row = p >> 6, cl = p & 63;
            int d8 = cl ^ (row & 7);
            uint4 vv = *(const uint4*)(xnb + (size_t)(k0 + row) * DH + d8 * 8);
            *(uint4*)&knL[row * 512 + cl * 8] = vv;
        }
        // ---- stage Kn^T [row=d][kk] ----
        #pragma unroll
        for (int i = 0; i < 16; i++) {
            int p = i * 256 + tid;
            int dr = p >> 3, c8 = p & 7;
            int k8 = c8 ^ (dr & 7);
            uint4 vv = *(const uint4*)(xtb + (size_t)dr * TT + k0 + k8 * 8);
            *(uint4*)&ktL[dr * 64 + c8 * 8] = vv;
        }
        // hoist V tile loads (independent of LDS)
        float vreg[4][4];
        #pragma unroll
        for (int f = 0; f < 4; f++)
            #pragma unroll
            for (int r = 0; r < 4; r++)
                vreg[f][r] = V[(size_t)(q0w + g * 4 + r) * TT + (k0 + f * 16 + lo)];
        __syncthreads();

        // ---- step 1: S = Qn * Kn^T  (reduce over d) ----
        floatx4 sacc[4];
        #pragma unroll
        for (int f = 0; f < 4; f++) sacc[f] = (floatx4){0.f, 0.f, 0.f, 0.f};
        #pragma unroll
        for (int s = 0; s < 16; s++) {
            int ch = (s * 4 + g) ^ sx;
            #pragma unroll
            for (int f = 0; f < 4; f++) {
                half8 bf = *(const half8*)&knL[(f * 16 + lo) * 512 + ch * 8];
                sacc[f] = __builtin_amdgcn_mfma_f32_16x16x32_f16(qf[s], bf, sacc[f], 0, 0, 0);
            }
        }

        // ---- step 2: W = V .* S -> per-wave LDS scratch (fp16) ----
        #pragma unroll
        for (int f = 0; f < 4; f++) {
            int kk = f * 16 + lo;
            #pragma unroll
            for (int r = 0; r < 4; r++) {
                int q_ = g * 4 + r;
                wt[q_ * 80 + (((kk >> 3) ^ (q_ & 7)) * 8) + (kk & 7)] = f2h(sacc[f][r] * vreg[f][r]);
            }
        }

        // ---- step 3: ctx += W * Kn  (reduce over kk) ----
        #pragma unroll
        for (int s3 = 0; s3 < 2; s3++) {
            int ch = (s3 * 4 + g) ^ sx;
            half8 af = *(const half8*)&wt[lo * 80 + ch * 8];
            #pragma unroll
            for (int n = 0; n < 32; n++) {
                half8 bf = *(const half8*)&ktL[(n * 16 + lo) * 64 + ch * 8];
                acc[n] = __builtin_amdgcn_mfma_f32_16x16x32_f16(af, bf, acc[n], 0, 0, 0);
            }
        }
        __syncthreads();
    }

    // ---- epilogue: out = x_left * sigmoid(ctx + bias) ----
    const float* xb = x + (size_t)b * TT * 1024;
    float* ob = out + (size_t)b * TT * DH;
    #pragma unroll
    for (int n = 0; n < 32; n++) {
        int d = n * 16 + lo;
        float bv = bias[d];
        #pragma unroll
        for (int r = 0; r < 4; r++) {
            int q = q0w + g * 4 + r;
            float cv = acc[n][r] + bv;
            float gate = 1.0f / (1.0f + __expf(-cv));
            ob[(size_t)q * DH + d] = xb[(size_t)q * 1024 + d] * gate;
        }
    }
}

extern "C" void kernel_launch(void* const* d_in, const int* in_sizes, int n_in,
                              void* d_out, int out_size, void* d_ws, size_t ws_size,
                              hipStream_t stream) {
    const float* x    = (const float*)d_in[0];
    const float* V    = (const float*)d_in[1];
    const float* bias = (const float*)d_in[2];
    float* out = (float*)d_out;

    unsigned short* xn  = (unsigned short*)d_ws;              // [4][4096][512] fp16
    unsigned short* xnT = xn + (size_t)4 * TT * DH;           // [4][512][4096] fp16

    norm_k<<<dim3(4 * TT / 4), 256, 0, stream>>>(x, xn);
    transpose_k<<<dim3(TT / 64, DH / 64, 4), 256, 0, stream>>>(xn, xnT);
    fused_k<<<dim3(TT / 64, 4), 256, 0, stream>>>(xn, xnT, V, bias, x, out);
}

// Round 2
// 247.473 us; speedup vs baseline: 1.7010x; 1.7010x over previous
//
#include <hip/hip_runtime.h>
#include <stdint.h>

typedef _Float16 half8 __attribute__((ext_vector_type(8)));
typedef _Float16 half4v __attribute__((ext_vector_type(4)));
typedef float floatx4 __attribute__((ext_vector_type(4)));
typedef float floatx16 __attribute__((ext_vector_type(16)));

#define TT 4096
#define DH 512

#define WAITVM(n) asm volatile("s_waitcnt vmcnt(" #n ")" ::: "memory")
#define WAITLGKM() asm volatile("s_waitcnt lgkmcnt(0)" ::: "memory")
#define BAR() __builtin_amdgcn_s_barrier()

__device__ __forceinline__ unsigned short f2h(float f) {
    union { _Float16 h; unsigned short u; } v;
    v.h = (_Float16)f;
    return v.u;
}

// ---------- kernel 1: normalize right half of x -> xn (fp16), one wave per row ----------
__global__ void norm_k(const float* __restrict__ x, unsigned short* __restrict__ xn) {
    const int w = threadIdx.x >> 6, l = threadIdx.x & 63;
    const int row = blockIdx.x * 4 + w;              // 0 .. B*T-1
    const float* src = x + (size_t)row * 1024 + 512 + l * 8;
    floatx4 a = *(const floatx4*)src;
    floatx4 c = *(const floatx4*)(src + 4);
    float s = a[0]*a[0] + a[1]*a[1] + a[2]*a[2] + a[3]*a[3]
            + c[0]*c[0] + c[1]*c[1] + c[2]*c[2] + c[3]*c[3];
    #pragma unroll
    for (int off = 32; off > 0; off >>= 1) s += __shfl_xor(s, off);
    const float scale = 1.0f / fmaxf(sqrtf(s), 1e-12f);
    float v[8] = {a[0], a[1], a[2], a[3], c[0], c[1], c[2], c[3]};
    uint32_t pk[4];
    #pragma unroll
    for (int i = 0; i < 4; i++)
        pk[i] = (uint32_t)f2h(v[2*i] * scale) | ((uint32_t)f2h(v[2*i+1] * scale) << 16);
    uint4 o; o.x = pk[0]; o.y = pk[1]; o.z = pk[2]; o.w = pk[3];
    *(uint4*)(xn + (size_t)row * DH + l * 8) = o;
}

// ---------- kernel 2: xnT[b][d][t] = xn[b][t][d], 64x64 LDS tile transpose ----------
__global__ void transpose_k(const unsigned short* __restrict__ xn,
                            unsigned short* __restrict__ xnT) {
    __shared__ __align__(16) unsigned short tile[64 * 72];  // +8 pad
    const int b = blockIdx.z;
    const int t0 = blockIdx.x * 64, d0 = blockIdx.y * 64;
    const int tid = threadIdx.x;
    #pragma unroll
    for (int i = 0; i < 2; i++) {
        int c = i * 256 + tid;
        int tr = c >> 3, d8 = c & 7;
        uint4 vv = *(const uint4*)(xn + ((size_t)(b * TT + t0 + tr) * DH + d0 + d8 * 8));
        *(uint4*)&tile[tr * 72 + d8 * 8] = vv;
    }
    __syncthreads();
    #pragma unroll
    for (int i = 0; i < 2; i++) {
        int c = i * 256 + tid;
        int dd = c >> 3, t8 = c & 7;
        uint32_t pk[4];
        #pragma unroll
        for (int k = 0; k < 4; k++) {
            uint32_t h0 = tile[(t8 * 8 + 2 * k    ) * 72 + dd];
            uint32_t h1 = tile[(t8 * 8 + 2 * k + 1) * 72 + dd];
            pk[k] = h0 | (h1 << 16);
        }
        uint4 o; o.x = pk[0]; o.y = pk[1]; o.z = pk[2]; o.w = pk[3];
        *(uint4*)(xnT + ((size_t)(b * DH + d0 + dd) * TT + t0 + t8 * 8)) = o;
    }
}

// ---------- kernel 3: fused  ctx = (V .* (Q Kn^T)) Kn ;  out = x_left * sigmoid(ctx+bias) ----------
// 512 threads = 8 waves. Wave w owns d-slice [w*64, w*64+64).
// Per k-tile (64 kk):
//   step1: S^T[kk 64][q 64] partial over wave's 64 d, via mfma(A=Kn, B=Q) -> C rows = kk runs
//   Sred:  8 fp16 partials in LDS (overlaid on knL, 4-chunk XOR swizzle), reduced by 512 thr
//   W = V .* S  -> row-major [64 q][72 kk-pad] fp16
//   step3: ctx[q][wave's 64 d] += W * Kn  (B from ktL = Kn^T staged)
// Staging via global_load_lds(16B), src-swizzled; kn[t+1] overlaps step3, kt[t] stays
// in flight through step1+reduce (counted vmcnt, drained only before step3).
__global__ __launch_bounds__(512, 2) void fused_k(
    const unsigned short* __restrict__ xn, const unsigned short* __restrict__ xnT,
    const float* __restrict__ V, const float* __restrict__ bias,
    const float* __restrict__ x, float* __restrict__ out)
{
    // LDS: ktL [512 d][64 kk] = 64 KiB | knL [64 kk][512 d] = 64 KiB (aliased by Sred
    // [8 dg][64 q][64 kk] fp16 after step1) | W [64 q][72] fp16 = 9 KiB
    __shared__ __align__(16) unsigned short smem[70144];
    unsigned short* ktL = smem;            // 32768 u16
    unsigned short* knL = smem + 32768;    // 32768 u16
    unsigned short* Wl  = smem + 65536;    // 4608 u16

    const int tid = threadIdx.x;
    const int w = tid >> 6, l = tid & 63;
    const int h = l >> 5;           // k-half within fragment
    const int m32 = l & 31;         // fragment row/col lane
    // XCD-aware swizzle: 256 blocks -> XCD j gets 32 consecutive works (same batch)
    const int flat = blockIdx.y * 64 + blockIdx.x;
    const int work = (flat & 7) * 32 + (flat >> 3);
    const int b = work >> 6, qt = work & 63;
    const int q0 = qt * 64;

    const unsigned short* xnb = xn  + (size_t)b * TT * DH;
    const unsigned short* xtb = xnT + (size_t)b * DH * TT;

    // reduce-phase thread mapping
    const int tq = tid >> 3, to = tid & 7;
    const float* vrow = V + (size_t)(q0 + tq) * TT + to * 8;

    // ---- prologue: Q fragments (B-operand: B[k=d][n=q], lane: q=m32, d=w*64+ks*16+h*8+j)
    half8 qf[2][4];
    #pragma unroll
    for (int ni = 0; ni < 2; ni++)
        #pragma unroll
        for (int ks = 0; ks < 4; ks++)
            qf[ni][ks] = *(const half8*)(xnb + (size_t)(q0 + ni*32 + m32) * DH
                                         + w*64 + ks*16 + h*8);

    // issue kn[0] staging: wave w rows w*8..w*8+7; lds chunk l <- global chunk l^(r&7)
    #pragma unroll
    for (int i = 0; i < 8; i++) {
        int r = w * 8 + i;
        const unsigned short* g = xnb + (size_t)r * DH + ((l ^ (r & 7)) * 8);
        __builtin_amdgcn_global_load_lds(
            (const __attribute__((address_space(1))) void*)g,
            (__attribute__((address_space(3))) void*)&knL[r * 512], 16, 0, 0);
    }

    floatx16 acc[2][2];
    #pragma unroll
    for (int mi = 0; mi < 2; mi++)
        #pragma unroll
        for (int ni = 0; ni < 2; ni++)
            acc[mi][ni] = (floatx16)(0.f);

    #pragma unroll 1
    for (int t = 0; t < 64; t++) {
        const int k0 = t * 64;

        // ---- issue V[t] (2 loads) and kt[t] (8 gll) ----
        floatx4 va = *(const floatx4*)(vrow + k0);
        floatx4 vb = *(const floatx4*)(vrow + k0 + 4);
        #pragma unroll
        for (int i = 0; i < 8; i++) {
            int r0 = (w * 8 + i) * 8;               // 8 d-rows per gll
            int dr = r0 + (l >> 3);
            const unsigned short* g = xtb + (size_t)dr * TT + k0 + (((l & 7) ^ (dr & 7)) * 8);
            __builtin_amdgcn_global_load_lds(
                (const __attribute__((address_space(1))) void*)g,
                (__attribute__((address_space(3))) void*)&ktL[r0 * 64], 16, 0, 0);
        }

        // ---- kn ready (leave V+kt=10 in flight) ----
        WAITVM(10);
        BAR();

        // ---- step1: S^T partial = Kn * Q^T over wave's d-slice ----
        floatx16 sacc[2][2];
        #pragma unroll
        for (int mi = 0; mi < 2; mi++)
            #pragma unroll
            for (int ni = 0; ni < 2; ni++)
                sacc[mi][ni] = (floatx16)(0.f);
        __builtin_amdgcn_s_setprio(1);
        #pragma unroll
        for (int ks = 0; ks < 4; ks++) {
            half8 af[2];
            #pragma unroll
            for (int mi = 0; mi < 2; mi++) {
                int row = mi * 32 + m32;            // kk
                int cl = w * 8 + ks * 2 + h;        // logical d-chunk
                af[mi] = *(const half8*)&knL[row * 512 + (cl ^ (row & 7)) * 8];
            }
            #pragma unroll
            for (int mi = 0; mi < 2; mi++)
                #pragma unroll
                for (int ni = 0; ni < 2; ni++)
                    sacc[mi][ni] = __builtin_amdgcn_mfma_f32_32x32x16_f16(
                        af[mi], qf[ni][ks], sacc[mi][ni], 0, 0, 0);
        }
        __builtin_amdgcn_s_setprio(0);

        WAITLGKM();
        BAR();   // all knL reads done -> safe to overlay Sred

        // ---- Sred writes: [dg=w][q][kk], chunk-of-4 swizzled by (q&7)<<1 ----
        #pragma unroll
        for (int mi = 0; mi < 2; mi++)
            #pragma unroll
            for (int ni = 0; ni < 2; ni++) {
                int q = ni * 32 + m32;
                int sw = (q & 7) << 1;
                #pragma unroll
                for (int rr = 0; rr < 4; rr++) {
                    int b4 = mi * 8 + rr * 2 + h;   // kk chunk-of-4 (kk run = b4*4)
                    half4v v4;
                    v4[0] = (_Float16)sacc[mi][ni][rr*4+0];
                    v4[1] = (_Float16)sacc[mi][ni][rr*4+1];
                    v4[2] = (_Float16)sacc[mi][ni][rr*4+2];
                    v4[3] = (_Float16)sacc[mi][ni][rr*4+3];
                    *(half4v*)&knL[w * 4096 + q * 64 + (b4 ^ sw) * 4] = v4;
                }
            }
        WAITLGKM();
        BAR();   // Sred ready

        // ---- reduce 8 partials, multiply V, write W [64][72] fp16 ----
        {
            float s8[8] = {0,0,0,0,0,0,0,0};
            int base4 = (to * 2) ^ ((tq & 7) << 1);   // even -> pair stays contiguous
            #pragma unroll
            for (int dg = 0; dg < 8; dg++) {
                half8 v = *(const half8*)&knL[dg * 4096 + tq * 64 + base4 * 4];
                #pragma unroll
                for (int j = 0; j < 8; j++) s8[j] += (float)v[j];
            }
            half8 wv;
            wv[0] = (_Float16)(s8[0] * va[0]); wv[1] = (_Float16)(s8[1] * va[1]);
            wv[2] = (_Float16)(s8[2] * va[2]); wv[3] = (_Float16)(s8[3] * va[3]);
            wv[4] = (_Float16)(s8[4] * vb[0]); wv[5] = (_Float16)(s8[5] * vb[1]);
            wv[6] = (_Float16)(s8[6] * vb[2]); wv[7] = (_Float16)(s8[7] * vb[3]);
            *(half8*)&Wl[tq * 72 + to * 8] = wv;
        }
        WAITLGKM();

        // ---- issue kn[t+1] (knL region free), then drain kt[t] ----
        if (t < 63) {
            #pragma unroll
            for (int i = 0; i < 8; i++) {
                int r = w * 8 + i;
                const unsigned short* g = xnb + (size_t)(k0 + 64 + r) * DH + ((l ^ (r & 7)) * 8);
                __builtin_amdgcn_global_load_lds(
                    (const __attribute__((address_space(1))) void*)g,
                    (__attribute__((address_space(3))) void*)&knL[r * 512], 16, 0, 0);
            }
            WAITVM(8);      // kt[t] landed, kn[t+1] in flight
        } else {
            WAITVM(0);
        }
        BAR();   // W ready + ktL ready block-wide

        // ---- step3: ctx[q][wave d-slice] += W * Kn ----
        __builtin_amdgcn_s_setprio(1);
        #pragma unroll
        for (int ks = 0; ks < 4; ks++) {
            half8 wf[2], bf[2];
            #pragma unroll
            for (int mi = 0; mi < 2; mi++)
                wf[mi] = *(const half8*)&Wl[(mi * 32 + m32) * 72 + (ks * 2 + h) * 8];
            #pragma unroll
            for (int ni = 0; ni < 2; ni++) {
                int row = w * 64 + ni * 32 + m32;   // d
                bf[ni] = *(const half8*)&ktL[row * 64 + ((ks * 2 + h) ^ (row & 7)) * 8];
            }
            #pragma unroll
            for (int mi = 0; mi < 2; mi++)
                #pragma unroll
                for (int ni = 0; ni < 2; ni++)
                    acc[mi][ni] = __builtin_amdgcn_mfma_f32_32x32x16_f16(
                        wf[mi], bf[ni], acc[mi][ni], 0, 0, 0);
        }
        __builtin_amdgcn_s_setprio(0);
        BAR();   // step3 reads done -> next tile may restage ktL
    }

    // ---- epilogue: out = x_left * sigmoid(ctx + bias) ----
    const float* xb = x + (size_t)b * TT * 1024;
    float* ob = out + (size_t)b * TT * DH;
    #pragma unroll
    for (int mi = 0; mi < 2; mi++)
        #pragma unroll
        for (int ni = 0; ni < 2; ni++) {
            int d = w * 64 + ni * 32 + m32;
            float bv = bias[d];
            #pragma unroll
            for (int r = 0; r < 16; r++) {
                int q = q0 + mi * 32 + (r & 3) + 8 * (r >> 2) + 4 * h;
                float cv = acc[mi][ni][r] + bv;
                float gate = 1.0f / (1.0f + __expf(-cv));
                ob[(size_t)q * DH + d] = xb[(size_t)q * 1024 + d] * gate;
            }
        }
}

extern "C" void kernel_launch(void* const* d_in, const int* in_sizes, int n_in,
                              void* d_out, int out_size, void* d_ws, size_t ws_size,
                              hipStream_t stream) {
    const float* x    = (const float*)d_in[0];
    const float* V    = (const float*)d_in[1];
    const float* bias = (const float*)d_in[2];
    float* out = (float*)d_out;

    unsigned short* xn  = (unsigned short*)d_ws;              // [4][4096][512] fp16
    unsigned short* xnT = xn + (size_t)4 * TT * DH;           // [4][512][4096] fp16

    norm_k<<<dim3(4 * TT / 4), 256, 0, stream>>>(x, xn);
    transpose_k<<<dim3(TT / 64, DH / 64, 4), 256, 0, stream>>>(xn, xnT);
    fused_k<<<dim3(TT / 64, 4), 512, 0, stream>>>(xn, xnT, V, bias, x, out);
}